// Round 3
// baseline (2473.752 us; speedup 1.0000x reference)
//
#include <hip/hip_runtime.h>
#include <hip/hip_bf16.h>

// Problem constants
#define BB 64
#define TT 256
#define HH 256
#define LL 15
#define E300 300
#define KPAD 608              // 600 padded to multiple of 32 (19 k-steps of 32)
#define NG 2048               // 2 directions * 4H gates
#define MROWS 16384           // B*T

typedef float  floatx4 __attribute__((ext_vector_type(4)));
typedef __bf16 bf16x8  __attribute__((ext_vector_type(8)));

// ALL float tensor inputs are float32 (per reference file: jnp.float32).
// Round-1 experiment proved output is float32; round-2 NaN was float32 inputs
// misread as bf16 (mantissa bits hitting bf16 NaN patterns).
// Internally we cast to bf16 for the MFMA GEMM and packed recurrent weights.

// ---------------- prep kernels ----------------

// X[row][0..299]=bf16(emb[id]), [300..599]=bf16(soft_emb[sid]), [600..607]=0
__global__ void k_embed(const int* __restrict__ ids, const int* __restrict__ sids,
                        const float* __restrict__ emb,
                        const float* __restrict__ semb,
                        __hip_bfloat16* __restrict__ X) {
    int row = blockIdx.x;
    int id  = ids[row];
    int sid = sids[row];
    const float* e0 = emb  + (long)id  * E300;
    const float* e1 = semb + (long)sid * E300;
    __hip_bfloat16* xr = X + (long)row * KPAD;
    for (int c = threadIdx.x; c < KPAD; c += blockDim.x) {
        float v;
        if (c < 300)      v = e0[c];
        else if (c < 600) v = e1[c - 300];
        else              v = 0.f;
        xr[c] = __float2bfloat16(v);
    }
}

// Wcat[2048][608]: rows 0..1023 = Wih_f (i,f,g,o), 1024..2047 = Wih_b; k padded w/ 0
__global__ void k_wcat(const float* __restrict__ Wf,
                       const float* __restrict__ Wb,
                       __hip_bfloat16* __restrict__ Wcat) {
    int r = blockIdx.x;
    const float* src = (r < 1024) ? (Wf + (long)r * 600)
                                  : (Wb + (long)(r - 1024) * 600);
    __hip_bfloat16* dst = Wcat + (long)r * KPAD;
    for (int c = threadIdx.x; c < KPAD; c += blockDim.x)
        dst[c] = __float2bfloat16((c < 600) ? src[c] : 0.f);
}

// Wpk[dir][k][j][g] = bf16(Whh_dir[g*256 + j][k])   (gate-interleaved, k-major)
__global__ void k_wpk(const float* __restrict__ Wf,
                      const float* __restrict__ Wb,
                      __hip_bfloat16* __restrict__ Wpk) {
    int d = blockIdx.x >> 8;
    int k = blockIdx.x & 255;
    int j = threadIdx.x;
    const float* W = d ? Wb : Wf;
    __hip_bfloat16* out = Wpk + (((long)(d * 256 + k)) * 256 + j) * 4;
    #pragma unroll
    for (int g = 0; g < 4; ++g)
        out[g] = __float2bfloat16(W[((long)(g * 256 + j)) * 256 + k]);
}

// bias[dir][j4] = bih + bhh (fp32)
__global__ void k_bias(const float* __restrict__ bfi, const float* __restrict__ bfh,
                       const float* __restrict__ bbi, const float* __restrict__ bbh,
                       float* __restrict__ bias) {
    int i = blockIdx.x * blockDim.x + threadIdx.x;
    if (i < 2048) {
        int d = i >> 10, j = i & 1023;
        const float* b1 = d ? bbi : bfi;
        const float* b2 = d ? bbh : bfh;
        bias[i] = b1[j] + b2[j];
    }
}

// ---------------- input GEMM:  G[16384][2048] = X[16384][608] * Wcat[2048][608]^T ----------------
__global__ __launch_bounds__(256) void k_gemm(const __hip_bfloat16* __restrict__ A,
                                              const __hip_bfloat16* __restrict__ Bw,
                                              __hip_bfloat16* __restrict__ C) {
    __shared__ __align__(16) unsigned short As[128 * 40];  // 128 x 32, row stride 40 (pad)
    __shared__ __align__(16) unsigned short Bs[128 * 40];
    int bm = blockIdx.x, bn = blockIdx.y;
    int row0 = bm * 128, col0 = bn * 128;
    int tid = threadIdx.x;
    int wave = tid >> 6, lane = tid & 63;
    int wm = (wave >> 1) * 64, wn = (wave & 1) * 64;
    int l15 = lane & 15, quad = lane >> 4;
    floatx4 acc[4][4];
    #pragma unroll
    for (int i = 0; i < 4; ++i)
        #pragma unroll
        for (int j = 0; j < 4; ++j) acc[i][j] = (floatx4){0.f, 0.f, 0.f, 0.f};

    int r1 = tid >> 2, p1 = tid & 3;  // staging: chunk row / 16B-part

    for (int kk = 0; kk < KPAD; kk += 32) {
        uint4 a0 = *(const uint4*)(A  + ((long)(row0 + r1))      * KPAD + kk + p1 * 8);
        uint4 a1 = *(const uint4*)(A  + ((long)(row0 + 64 + r1)) * KPAD + kk + p1 * 8);
        uint4 b0 = *(const uint4*)(Bw + ((long)(col0 + r1))      * KPAD + kk + p1 * 8);
        uint4 b1 = *(const uint4*)(Bw + ((long)(col0 + 64 + r1)) * KPAD + kk + p1 * 8);
        *(uint4*)&As[r1 * 40 + p1 * 8]        = a0;
        *(uint4*)&As[(64 + r1) * 40 + p1 * 8] = a1;
        *(uint4*)&Bs[r1 * 40 + p1 * 8]        = b0;
        *(uint4*)&Bs[(64 + r1) * 40 + p1 * 8] = b1;
        __syncthreads();
        bf16x8 af[4], bfr[4];
        #pragma unroll
        for (int tm = 0; tm < 4; ++tm)
            af[tm] = *(const bf16x8*)&As[(wm + tm * 16 + l15) * 40 + quad * 8];
        #pragma unroll
        for (int tn = 0; tn < 4; ++tn)
            bfr[tn] = *(const bf16x8*)&Bs[(wn + tn * 16 + l15) * 40 + quad * 8];
        #pragma unroll
        for (int tm = 0; tm < 4; ++tm)
            #pragma unroll
            for (int tn = 0; tn < 4; ++tn)
                acc[tm][tn] = __builtin_amdgcn_mfma_f32_16x16x32_bf16(af[tm], bfr[tn], acc[tm][tn], 0, 0, 0);
        __syncthreads();
    }
    // C/D layout: m = quad*4 + reg, n = lane&15
    #pragma unroll
    for (int tm = 0; tm < 4; ++tm)
        #pragma unroll
        for (int tn = 0; tn < 4; ++tn) {
            int m0 = row0 + wm + tm * 16 + quad * 4;
            int n  = col0 + wn + tn * 16 + l15;
            #pragma unroll
            for (int r = 0; r < 4; ++r)
                C[((long)(m0 + r)) * NG + n] = __float2bfloat16(acc[tm][tn][r]);
        }
}

// ---------------- LSTM recurrence: one block per (batch, direction) ----------------
__global__ __launch_bounds__(256) void k_lstm(const __hip_bfloat16* __restrict__ G,    // [MROWS][NG]
                                              const __hip_bfloat16* __restrict__ Wpk,  // [2][256][256][4]
                                              const float* __restrict__ bias,          // [2][1024]
                                              const int* __restrict__ lengths,
                                              __hip_bfloat16* __restrict__ Hout) {     // [B][T][512]
    int dir = blockIdx.x & 1;
    int b   = blockIdx.x >> 1;
    int j   = threadIdx.x;   // hidden unit
    __shared__ float hs[HH];
    hs[j] = 0.f;
    float c = 0.f;
    const float* bs = bias + dir * 1024;
    float bi = bs[j], bf_ = bs[256 + j], bg = bs[512 + j], bo = bs[768 + j];
    int len = lengths[b];
    const uint2* wp = (const uint2*)(Wpk + (long)dir * 256 * 1024) + j;  // [k][j] -> 4 gates (8B)
    __syncthreads();
    for (int t = 0; t < TT; ++t) {
        int tt = t;
        if (dir) tt = (t < len) ? (len - 1 - t) : t;
        const __hip_bfloat16* g = G + ((long)(b * TT + tt)) * NG + dir * 1024;
        float ai = bi  + __bfloat162float(g[j]);
        float af = bf_ + __bfloat162float(g[256 + j]);
        float ag = bg  + __bfloat162float(g[512 + j]);
        float ao = bo  + __bfloat162float(g[768 + j]);
        #pragma unroll 8
        for (int k = 0; k < HH; ++k) {
            float hk = hs[k];
            uint2 w = wp[k * 256];
            float w0 = __uint_as_float(w.x << 16);
            float w1 = __uint_as_float(w.x & 0xffff0000u);
            float w2 = __uint_as_float(w.y << 16);
            float w3 = __uint_as_float(w.y & 0xffff0000u);
            ai = fmaf(hk, w0, ai);
            af = fmaf(hk, w1, af);
            ag = fmaf(hk, w2, ag);
            ao = fmaf(hk, w3, ao);
        }
        float ii = 1.f / (1.f + __expf(-ai));
        float ff = 1.f / (1.f + __expf(-af));
        float gg = tanhf(ag);
        float oo = 1.f / (1.f + __expf(-ao));
        c = ff * c + ii * gg;
        float h = oo * tanhf(c);
        __syncthreads();           // all matvec reads of hs done
        hs[j] = h;
        Hout[((long)(b * TT + tt)) * 512 + dir * HH + j] = __float2bfloat16(h);
        __syncthreads();           // new hs visible
    }
}

// ---------------- emissions: E[row][l] = h[row][0..511] . Wlin[l][0..511] + blin[l] ----------------
__global__ void k_emis(const __hip_bfloat16* __restrict__ Hc,   // [MROWS][512]
                       const float* __restrict__ Wlin,          // [15][512] fp32
                       const float* __restrict__ blin,
                       float* __restrict__ E) {
    int gid = blockIdx.x * blockDim.x + threadIdx.x;
    if (gid >= MROWS * LL) return;
    int row = gid / LL;
    int l = gid - row * LL;
    const __hip_bfloat16* hr = Hc + (long)row * 512;
    const float* wr = Wlin + l * 512;
    float s = blin[l];
    #pragma unroll 8
    for (int k = 0; k < 512; ++k)
        s = fmaf(__bfloat162float(hr[k]), wr[k], s);
    E[gid] = s;
}

// ---------------- CRF NLL per batch: one wave per batch ----------------
__global__ void k_crf(const float* __restrict__ E,      // [B][T][15]
                      const int* __restrict__ tags,     // [B][T]
                      const int* __restrict__ lengths,
                      const float* __restrict__ start_t,
                      const float* __restrict__ end_t,
                      const float* __restrict__ trans,  // [15][15] fp32
                      float* __restrict__ outp) {
    int b = blockIdx.x;
    int lane = threadIdx.x;
    int len = lengths[b];
    const float* Eb = E + (long)b * TT * LL;
    const int* tg = tags + b * TT;
    float tcol[LL];
    #pragma unroll
    for (int k = 0; k < LL; ++k)
        tcol[k] = (lane < LL) ? trans[k * LL + lane] : 0.f;
    float alpha = (lane < LL) ? start_t[lane] + Eb[lane] : -1e30f;
    for (int t = 1; t < len; ++t) {
        float e = (lane < LL) ? Eb[t * LL + lane] : 0.f;
        float m = -1e30f;
        float v[LL];
        #pragma unroll
        for (int k = 0; k < LL; ++k) {
            float ak = __shfl(alpha, k, 64);
            v[k] = ak + tcol[k];
            m = fmaxf(m, v[k]);
        }
        float s = 0.f;
        #pragma unroll
        for (int k = 0; k < LL; ++k) s += __expf(v[k] - m);
        alpha = m + __logf(s) + e;
    }
    // denominator
    float z = alpha + ((lane < LL) ? end_t[lane] : -1e30f);
    float m2 = -1e30f;
    #pragma unroll
    for (int k = 0; k < LL; ++k) m2 = fmaxf(m2, __shfl(z, k, 64));
    float s2 = 0.f;
    #pragma unroll
    for (int k = 0; k < LL; ++k) s2 += __expf(__shfl(z, k, 64) - m2);
    float den = m2 + __logf(s2);
    // numerator (lane-parallel over t, then wave-reduce)
    float part = 0.f;
    for (int t = lane; t < TT; t += 64) {
        if (t < len) {
            int tag = tg[t];
            part += Eb[t * LL + tag];
            if (t >= 1) part += trans[tg[t - 1] * LL + tag];
        }
    }
    #pragma unroll
    for (int off = 32; off > 0; off >>= 1) part += __shfl_down(part, off, 64);
    if (lane == 0) {
        float num = part + start_t[tg[0]] + end_t[tg[len - 1]];
        outp[b] = num - den;
    }
}

// output is float32 (reference output dtype)
__global__ void k_final(const float* __restrict__ outp, float* __restrict__ out) {
    int lane = threadIdx.x;
    float v = outp[lane];
    #pragma unroll
    for (int off = 32; off > 0; off >>= 1) v += __shfl_down(v, off, 64);
    if (lane == 0) out[0] = -v;   // loss = -sum(num - den)
}

// ---------------- launch ----------------
extern "C" void kernel_launch(void* const* d_in, const int* in_sizes, int n_in,
                              void* d_out, int out_size, void* d_ws, size_t ws_size,
                              hipStream_t stream) {
    const int* input_ids    = (const int*)d_in[0];
    const int* lengths      = (const int*)d_in[1];
    const int* softword_ids = (const int*)d_in[2];
    const int* label_ids    = (const int*)d_in[3];
    const float* emb      = (const float*)d_in[4];
    const float* soft_emb = (const float*)d_in[5];
    const float* Wih_f = (const float*)d_in[6];
    const float* Whh_f = (const float*)d_in[7];
    const float* bih_f = (const float*)d_in[8];
    const float* bhh_f = (const float*)d_in[9];
    const float* Wih_b = (const float*)d_in[10];
    const float* Whh_b = (const float*)d_in[11];
    const float* bih_b = (const float*)d_in[12];
    const float* bhh_b = (const float*)d_in[13];
    const float* Wlin  = (const float*)d_in[14];
    const float* blin  = (const float*)d_in[15];
    const float* start_t = (const float*)d_in[16];
    const float* end_t   = (const float*)d_in[17];
    const float* trans   = (const float*)d_in[18];

    // workspace layout, small buffers first (all offsets 256B aligned); total ~108.4 MB
    char* base = (char*)d_ws;
    float*          part = (float*)(base);                             // 64*4          =        256
    float*          bias = (float*)(base + 256);                       // 2*1024*4      =      8,192
    float*          E    = (float*)(base + 8448);                      // 16384*15*4    =    983,040
    __hip_bfloat16* Wpk  = (__hip_bfloat16*)(base + 991488);           // 2*256*1024*2  =  1,048,576
    __hip_bfloat16* Wcat = (__hip_bfloat16*)(base + 2040064);          // 2048*608*2    =  2,490,368
    __hip_bfloat16* Hc   = (__hip_bfloat16*)(base + 4530432);          // 64*256*512*2  = 16,777,216
    __hip_bfloat16* X    = (__hip_bfloat16*)(base + 21307648);         // 16384*608*2   = 19,922,944
    __hip_bfloat16* G    = (__hip_bfloat16*)(base + 41230592);         // 16384*2048*2  = 67,108,864
                                                                       // end: 108,339,456

    k_embed<<<MROWS, 64, 0, stream>>>(input_ids, softword_ids, emb, soft_emb, X);
    k_wcat<<<NG, 64, 0, stream>>>(Wih_f, Wih_b, Wcat);
    k_wpk<<<512, 256, 0, stream>>>(Whh_f, Whh_b, Wpk);
    k_bias<<<8, 256, 0, stream>>>(bih_f, bhh_f, bih_b, bhh_b, bias);
    k_gemm<<<dim3(MROWS / 128, NG / 128), 256, 0, stream>>>(X, Wcat, G);
    k_lstm<<<BB * 2, 256, 0, stream>>>(G, Wpk, bias, lengths, Hc);
    k_emis<<<(MROWS * LL) / 256, 256, 0, stream>>>(Hc, Wlin, blin, E);
    k_crf<<<BB, 64, 0, stream>>>(E, label_ids, lengths, start_t, end_t, trans, part);
    k_final<<<1, 64, 0, stream>>>(part, (float*)d_out);
}

// Round 4
// 2360.367 us; speedup vs baseline: 1.0480x; 1.0480x over previous
//
#include <hip/hip_runtime.h>
#include <hip/hip_bf16.h>

// Problem constants
#define BB 64
#define TT 256
#define HH 256
#define LL 15
#define E300 300
#define KPAD 608              // 600 padded to multiple of 32 (19 k-steps of 32)
#define NG 2048               // 2 directions * 4H gates
#define MROWS 16384           // B*T

typedef float  floatx4 __attribute__((ext_vector_type(4)));
typedef __bf16 bf16x8  __attribute__((ext_vector_type(8)));

// ALL float tensor inputs are float32 (per reference; proven rounds 1-3).
// Internally bf16 for MFMA GEMM + packed recurrent weights (absmax 0.0 margin).

// ---------------- prep kernels ----------------

// X[row][0..299]=bf16(emb[id]), [300..599]=bf16(soft_emb[sid]), [600..607]=0
__global__ void k_embed(const int* __restrict__ ids, const int* __restrict__ sids,
                        const float* __restrict__ emb,
                        const float* __restrict__ semb,
                        __hip_bfloat16* __restrict__ X) {
    int row = blockIdx.x;
    int id  = ids[row];
    int sid = sids[row];
    const float* e0 = emb  + (long)id  * E300;
    const float* e1 = semb + (long)sid * E300;
    __hip_bfloat16* xr = X + (long)row * KPAD;
    for (int c = threadIdx.x; c < KPAD; c += blockDim.x) {
        float v;
        if (c < 300)      v = e0[c];
        else if (c < 600) v = e1[c - 300];
        else              v = 0.f;
        xr[c] = __float2bfloat16(v);
    }
}

// Wcat[2048][608]: rows 0..1023 = Wih_f (i,f,g,o), 1024..2047 = Wih_b; k padded w/ 0
__global__ void k_wcat(const float* __restrict__ Wf,
                       const float* __restrict__ Wb,
                       __hip_bfloat16* __restrict__ Wcat) {
    int r = blockIdx.x;
    const float* src = (r < 1024) ? (Wf + (long)r * 600)
                                  : (Wb + (long)(r - 1024) * 600);
    __hip_bfloat16* dst = Wcat + (long)r * KPAD;
    for (int c = threadIdx.x; c < KPAD; c += blockDim.x)
        dst[c] = __float2bfloat16((c < 600) ? src[c] : 0.f);
}

// Wpk[dir][k][j][g] = bf16(Whh_dir[g*256 + j][k])   (gate-interleaved, k-major)
__global__ void k_wpk(const float* __restrict__ Wf,
                      const float* __restrict__ Wb,
                      __hip_bfloat16* __restrict__ Wpk) {
    int d = blockIdx.x >> 8;
    int k = blockIdx.x & 255;
    int j = threadIdx.x;
    const float* W = d ? Wb : Wf;
    __hip_bfloat16* out = Wpk + (((long)(d * 256 + k)) * 256 + j) * 4;
    #pragma unroll
    for (int g = 0; g < 4; ++g)
        out[g] = __float2bfloat16(W[((long)(g * 256 + j)) * 256 + k]);
}

// bias[dir][j4] = bih + bhh (fp32)
__global__ void k_bias(const float* __restrict__ bfi, const float* __restrict__ bfh,
                       const float* __restrict__ bbi, const float* __restrict__ bbh,
                       float* __restrict__ bias) {
    int i = blockIdx.x * blockDim.x + threadIdx.x;
    if (i < 2048) {
        int d = i >> 10, j = i & 1023;
        const float* b1 = d ? bbi : bfi;
        const float* b2 = d ? bbh : bfh;
        bias[i] = b1[j] + b2[j];
    }
}

// ---------------- input GEMM:  G[16384][2048] = X[16384][608] * Wcat[2048][608]^T ----------------
__global__ __launch_bounds__(256) void k_gemm(const __hip_bfloat16* __restrict__ A,
                                              const __hip_bfloat16* __restrict__ Bw,
                                              __hip_bfloat16* __restrict__ C) {
    __shared__ __align__(16) unsigned short As[128 * 40];  // 128 x 32, row stride 40 (pad)
    __shared__ __align__(16) unsigned short Bs[128 * 40];
    int bm = blockIdx.x, bn = blockIdx.y;
    int row0 = bm * 128, col0 = bn * 128;
    int tid = threadIdx.x;
    int wave = tid >> 6, lane = tid & 63;
    int wm = (wave >> 1) * 64, wn = (wave & 1) * 64;
    int l15 = lane & 15, quad = lane >> 4;
    floatx4 acc[4][4];
    #pragma unroll
    for (int i = 0; i < 4; ++i)
        #pragma unroll
        for (int j = 0; j < 4; ++j) acc[i][j] = (floatx4){0.f, 0.f, 0.f, 0.f};

    int r1 = tid >> 2, p1 = tid & 3;  // staging: chunk row / 16B-part

    for (int kk = 0; kk < KPAD; kk += 32) {
        uint4 a0 = *(const uint4*)(A  + ((long)(row0 + r1))      * KPAD + kk + p1 * 8);
        uint4 a1 = *(const uint4*)(A  + ((long)(row0 + 64 + r1)) * KPAD + kk + p1 * 8);
        uint4 b0 = *(const uint4*)(Bw + ((long)(col0 + r1))      * KPAD + kk + p1 * 8);
        uint4 b1 = *(const uint4*)(Bw + ((long)(col0 + 64 + r1)) * KPAD + kk + p1 * 8);
        *(uint4*)&As[r1 * 40 + p1 * 8]        = a0;
        *(uint4*)&As[(64 + r1) * 40 + p1 * 8] = a1;
        *(uint4*)&Bs[r1 * 40 + p1 * 8]        = b0;
        *(uint4*)&Bs[(64 + r1) * 40 + p1 * 8] = b1;
        __syncthreads();
        bf16x8 af[4], bfr[4];
        #pragma unroll
        for (int tm = 0; tm < 4; ++tm)
            af[tm] = *(const bf16x8*)&As[(wm + tm * 16 + l15) * 40 + quad * 8];
        #pragma unroll
        for (int tn = 0; tn < 4; ++tn)
            bfr[tn] = *(const bf16x8*)&Bs[(wn + tn * 16 + l15) * 40 + quad * 8];
        #pragma unroll
        for (int tm = 0; tm < 4; ++tm)
            #pragma unroll
            for (int tn = 0; tn < 4; ++tn)
                acc[tm][tn] = __builtin_amdgcn_mfma_f32_16x16x32_bf16(af[tm], bfr[tn], acc[tm][tn], 0, 0, 0);
        __syncthreads();
    }
    // C/D layout: m = quad*4 + reg, n = lane&15
    #pragma unroll
    for (int tm = 0; tm < 4; ++tm)
        #pragma unroll
        for (int tn = 0; tn < 4; ++tn) {
            int m0 = row0 + wm + tm * 16 + quad * 4;
            int n  = col0 + wn + tn * 16 + l15;
            #pragma unroll
            for (int r = 0; r < 4; ++r)
                C[((long)(m0 + r)) * NG + n] = __float2bfloat16(acc[tm][tn][r]);
        }
}

// ---------------- LSTM recurrence ----------------
// One block per (batch, direction), 1024 threads = 16 waves.
// Thread (q = tid>>8, j = tid&255): partial over k in [q*64, q*64+64) of the
// 4 gate pre-activations for hidden column j; 4-way LDS reduction per step.
// Rationale (R3): 4-wave version was 6% occupancy, VALUBusy 19.7%, 75% stall
// on L2 weight-load latency. 4 waves/SIMD hides it; issue floor ~5K cyc/step.
__global__ __launch_bounds__(1024) void k_lstm(const __hip_bfloat16* __restrict__ G,    // [MROWS][NG]
                                               const __hip_bfloat16* __restrict__ Wpk,  // [2][256][256][4]
                                               const float* __restrict__ bias,          // [2][1024]
                                               const int* __restrict__ lengths,
                                               __hip_bfloat16* __restrict__ Hout) {     // [B][T][512]
    int dir = blockIdx.x & 1;
    int b   = blockIdx.x >> 1;
    int tid = threadIdx.x;
    int q   = tid >> 8;        // k-quarter
    int j   = tid & 255;       // gate-unit column
    __shared__ float hs[HH];
    __shared__ __align__(16) float red[4][HH][4];   // [q][j][gate] = 16 KB
    float c = 0.f;
    float bi = 0.f, bf_ = 0.f, bg = 0.f, bo = 0.f;
    if (tid < HH) {
        const float* bs = bias + dir * 1024;
        bi = bs[j]; bf_ = bs[256 + j]; bg = bs[512 + j]; bo = bs[768 + j];
        hs[j] = 0.f;
    }
    int len = lengths[b];
    const uint2* wrow = (const uint2*)(Wpk + (long)dir * 256 * 1024) + q * 64 * 256 + j;
    const float* hq = hs + q * 64;
    __syncthreads();
    for (int t = 0; t < TT; ++t) {
        int tt = t;
        if (dir) tt = (t < len) ? (len - 1 - t) : t;
        const __hip_bfloat16* g = G + ((long)(b * TT + tt)) * NG + dir * 1024;
        float gi0 = 0.f, gi1 = 0.f, gi2 = 0.f, gi3 = 0.f;
        if (tid < HH) {   // prefetch gate inputs; consumed after the matvec
            gi0 = __bfloat162float(g[j]);
            gi1 = __bfloat162float(g[256 + j]);
            gi2 = __bfloat162float(g[512 + j]);
            gi3 = __bfloat162float(g[768 + j]);
        }
        float p0 = 0.f, p1 = 0.f, p2 = 0.f, p3 = 0.f;
        #pragma unroll 8
        for (int kk = 0; kk < 64; ++kk) {
            float hk = hq[kk];                 // LDS broadcast (same addr wave-wide)
            uint2 w = wrow[kk * 256];          // 64 lanes x 8B contiguous from L2
            p0 = fmaf(hk, __uint_as_float(w.x << 16),          p0);
            p1 = fmaf(hk, __uint_as_float(w.x & 0xffff0000u),  p1);
            p2 = fmaf(hk, __uint_as_float(w.y << 16),          p2);
            p3 = fmaf(hk, __uint_as_float(w.y & 0xffff0000u),  p3);
        }
        *(floatx4*)&red[q][j][0] = (floatx4){p0, p1, p2, p3};
        __syncthreads();
        if (tid < HH) {
            floatx4 r0 = *(const floatx4*)&red[0][j][0];
            floatx4 r1 = *(const floatx4*)&red[1][j][0];
            floatx4 r2 = *(const floatx4*)&red[2][j][0];
            floatx4 r3 = *(const floatx4*)&red[3][j][0];
            float ai = bi  + gi0 + r0[0] + r1[0] + r2[0] + r3[0];
            float af = bf_ + gi1 + r0[1] + r1[1] + r2[1] + r3[1];
            float ag = bg  + gi2 + r0[2] + r1[2] + r2[2] + r3[2];
            float ao = bo  + gi3 + r0[3] + r1[3] + r2[3] + r3[3];
            float ii = 1.f / (1.f + __expf(-ai));
            float ff = 1.f / (1.f + __expf(-af));
            float gg = tanhf(ag);
            float oo = 1.f / (1.f + __expf(-ao));
            c = ff * c + ii * gg;
            float h = oo * tanhf(c);
            hs[j] = h;
            Hout[((long)(b * TT + tt)) * 512 + dir * HH + j] = __float2bfloat16(h);
        }
        __syncthreads();
    }
}

// ---------------- emissions: E[row][l] = h[row][0..511] . Wlin[l][0..511] + blin[l] ----------------
__global__ void k_emis(const __hip_bfloat16* __restrict__ Hc,   // [MROWS][512]
                       const float* __restrict__ Wlin,          // [15][512] fp32
                       const float* __restrict__ blin,
                       float* __restrict__ E) {
    int gid = blockIdx.x * blockDim.x + threadIdx.x;
    if (gid >= MROWS * LL) return;
    int row = gid / LL;
    int l = gid - row * LL;
    const __hip_bfloat16* hr = Hc + (long)row * 512;
    const float* wr = Wlin + l * 512;
    float s = blin[l];
    #pragma unroll 8
    for (int k = 0; k < 512; ++k)
        s = fmaf(__bfloat162float(hr[k]), wr[k], s);
    E[gid] = s;
}

// ---------------- CRF NLL per batch: one wave per batch ----------------
__global__ void k_crf(const float* __restrict__ E,      // [B][T][15]
                      const int* __restrict__ tags,     // [B][T]
                      const int* __restrict__ lengths,
                      const float* __restrict__ start_t,
                      const float* __restrict__ end_t,
                      const float* __restrict__ trans,  // [15][15] fp32
                      float* __restrict__ outp) {
    int b = blockIdx.x;
    int lane = threadIdx.x;
    int len = lengths[b];
    const float* Eb = E + (long)b * TT * LL;
    const int* tg = tags + b * TT;
    float tcol[LL];
    #pragma unroll
    for (int k = 0; k < LL; ++k)
        tcol[k] = (lane < LL) ? trans[k * LL + lane] : 0.f;
    float alpha = (lane < LL) ? start_t[lane] + Eb[lane] : -1e30f;
    for (int t = 1; t < len; ++t) {
        float e = (lane < LL) ? Eb[t * LL + lane] : 0.f;
        float m = -1e30f;
        float v[LL];
        #pragma unroll
        for (int k = 0; k < LL; ++k) {
            float ak = __shfl(alpha, k, 64);
            v[k] = ak + tcol[k];
            m = fmaxf(m, v[k]);
        }
        float s = 0.f;
        #pragma unroll
        for (int k = 0; k < LL; ++k) s += __expf(v[k] - m);
        alpha = m + __logf(s) + e;
    }
    // denominator
    float z = alpha + ((lane < LL) ? end_t[lane] : -1e30f);
    float m2 = -1e30f;
    #pragma unroll
    for (int k = 0; k < LL; ++k) m2 = fmaxf(m2, __shfl(z, k, 64));
    float s2 = 0.f;
    #pragma unroll
    for (int k = 0; k < LL; ++k) s2 += __expf(__shfl(z, k, 64) - m2);
    float den = m2 + __logf(s2);
    // numerator (lane-parallel over t, then wave-reduce)
    float part = 0.f;
    for (int t = lane; t < TT; t += 64) {
        if (t < len) {
            int tag = tg[t];
            part += Eb[t * LL + tag];
            if (t >= 1) part += trans[tg[t - 1] * LL + tag];
        }
    }
    #pragma unroll
    for (int off = 32; off > 0; off >>= 1) part += __shfl_down(part, off, 64);
    if (lane == 0) {
        float num = part + start_t[tg[0]] + end_t[tg[len - 1]];
        outp[b] = num - den;
    }
}

// output is float32 (reference output dtype)
__global__ void k_final(const float* __restrict__ outp, float* __restrict__ out) {
    int lane = threadIdx.x;
    float v = outp[lane];
    #pragma unroll
    for (int off = 32; off > 0; off >>= 1) v += __shfl_down(v, off, 64);
    if (lane == 0) out[0] = -v;   // loss = -sum(num - den)
}

// ---------------- launch ----------------
extern "C" void kernel_launch(void* const* d_in, const int* in_sizes, int n_in,
                              void* d_out, int out_size, void* d_ws, size_t ws_size,
                              hipStream_t stream) {
    const int* input_ids    = (const int*)d_in[0];
    const int* lengths      = (const int*)d_in[1];
    const int* softword_ids = (const int*)d_in[2];
    const int* label_ids    = (const int*)d_in[3];
    const float* emb      = (const float*)d_in[4];
    const float* soft_emb = (const float*)d_in[5];
    const float* Wih_f = (const float*)d_in[6];
    const float* Whh_f = (const float*)d_in[7];
    const float* bih_f = (const float*)d_in[8];
    const float* bhh_f = (const float*)d_in[9];
    const float* Wih_b = (const float*)d_in[10];
    const float* Whh_b = (const float*)d_in[11];
    const float* bih_b = (const float*)d_in[12];
    const float* bhh_b = (const float*)d_in[13];
    const float* Wlin  = (const float*)d_in[14];
    const float* blin  = (const float*)d_in[15];
    const float* start_t = (const float*)d_in[16];
    const float* end_t   = (const float*)d_in[17];
    const float* trans   = (const float*)d_in[18];

    // workspace layout, small buffers first (all offsets 256B aligned); total ~108.4 MB
    char* base = (char*)d_ws;
    float*          part = (float*)(base);                             // 64*4          =        256
    float*          bias = (float*)(base + 256);                       // 2*1024*4      =      8,192
    float*          E    = (float*)(base + 8448);                      // 16384*15*4    =    983,040
    __hip_bfloat16* Wpk  = (__hip_bfloat16*)(base + 991488);           // 2*256*1024*2  =  1,048,576
    __hip_bfloat16* Wcat = (__hip_bfloat16*)(base + 2040064);          // 2048*608*2    =  2,490,368
    __hip_bfloat16* Hc   = (__hip_bfloat16*)(base + 4530432);          // 64*256*512*2  = 16,777,216
    __hip_bfloat16* X    = (__hip_bfloat16*)(base + 21307648);         // 16384*608*2   = 19,922,944
    __hip_bfloat16* G    = (__hip_bfloat16*)(base + 41230592);         // 16384*2048*2  = 67,108,864
                                                                       // end: 108,339,456

    k_embed<<<MROWS, 64, 0, stream>>>(input_ids, softword_ids, emb, soft_emb, X);
    k_wcat<<<NG, 64, 0, stream>>>(Wih_f, Wih_b, Wcat);
    k_wpk<<<512, 256, 0, stream>>>(Whh_f, Whh_b, Wpk);
    k_bias<<<8, 256, 0, stream>>>(bih_f, bhh_f, bih_b, bhh_b, bias);
    k_gemm<<<dim3(MROWS / 128, NG / 128), 256, 0, stream>>>(X, Wcat, G);
    k_lstm<<<BB * 2, 1024, 0, stream>>>(G, Wpk, bias, lengths, Hc);
    k_emis<<<(MROWS * LL) / 256, 256, 0, stream>>>(Hc, Wlin, blin, E);
    k_crf<<<BB, 64, 0, stream>>>(E, label_ids, lengths, start_t, end_t, trans, part);
    k_final<<<1, 64, 0, stream>>>(part, (float*)d_out);
}

// Round 5
// 1473.358 us; speedup vs baseline: 1.6790x; 1.6020x over previous
//
#include <hip/hip_runtime.h>
#include <hip/hip_bf16.h>

// Problem constants
#define BB 64
#define TT 256
#define HH 256
#define LL 15
#define E300 300
#define KPAD 608              // 600 padded to multiple of 32 (19 k-steps of 32)
#define NG 2048               // 2 directions * 4H gates
#define MROWS 16384           // B*T

typedef float  floatx4 __attribute__((ext_vector_type(4)));
typedef __bf16 bf16x8  __attribute__((ext_vector_type(8)));

// ALL float tensor inputs are float32 (per reference; proven rounds 1-3).
// R4 finding: k_lstm is per-CU L2-fetch-bound (~26 B/cyc/CU, invariant to wave
// count). Fix this round: fp8-e4m3 recurrent weights -> halve bytes/step.
// Weights scaled x16 into fp8 normal range; h stored as h/16 in LDS so the
// product (h/16)*(16w) = h*w needs no correction.

// ---------------- prep kernels ----------------

// X[row][0..299]=bf16(emb[id]), [300..599]=bf16(soft_emb[sid]), [600..607]=0
__global__ void k_embed(const int* __restrict__ ids, const int* __restrict__ sids,
                        const float* __restrict__ emb,
                        const float* __restrict__ semb,
                        __hip_bfloat16* __restrict__ X) {
    int row = blockIdx.x;
    int id  = ids[row];
    int sid = sids[row];
    const float* e0 = emb  + (long)id  * E300;
    const float* e1 = semb + (long)sid * E300;
    __hip_bfloat16* xr = X + (long)row * KPAD;
    for (int c = threadIdx.x; c < KPAD; c += blockDim.x) {
        float v;
        if (c < 300)      v = e0[c];
        else if (c < 600) v = e1[c - 300];
        else              v = 0.f;
        xr[c] = __float2bfloat16(v);
    }
}

// Wcat[2048][608]: rows 0..1023 = Wih_f (i,f,g,o), 1024..2047 = Wih_b; k padded w/ 0
__global__ void k_wcat(const float* __restrict__ Wf,
                       const float* __restrict__ Wb,
                       __hip_bfloat16* __restrict__ Wcat) {
    int r = blockIdx.x;
    const float* src = (r < 1024) ? (Wf + (long)r * 600)
                                  : (Wb + (long)(r - 1024) * 600);
    __hip_bfloat16* dst = Wcat + (long)r * KPAD;
    for (int c = threadIdx.x; c < KPAD; c += blockDim.x)
        dst[c] = __float2bfloat16((c < 600) ? src[c] : 0.f);
}

// Wpk8[dir][k][j] = packed fp8 e4m3 x4 gates: byte g = fp8(16 * Whh_dir[g*256+j][k])
__global__ void k_wpk(const float* __restrict__ Wf,
                      const float* __restrict__ Wb,
                      unsigned int* __restrict__ Wpk8) {
    int d = blockIdx.x >> 8;
    int k = blockIdx.x & 255;
    int j = threadIdx.x;
    const float* W = d ? Wb : Wf;
    float w0 = W[((long)(0 * 256 + j)) * 256 + k] * 16.f;
    float w1 = W[((long)(1 * 256 + j)) * 256 + k] * 16.f;
    float w2 = W[((long)(2 * 256 + j)) * 256 + k] * 16.f;
    float w3 = W[((long)(3 * 256 + j)) * 256 + k] * 16.f;
    int r = 0;
    r = __builtin_amdgcn_cvt_pk_fp8_f32(w0, w1, r, false);  // bytes 0,1 = i,f
    r = __builtin_amdgcn_cvt_pk_fp8_f32(w2, w3, r, true);   // bytes 2,3 = g,o
    Wpk8[((long)(d * 256 + k)) * 256 + j] = (unsigned int)r;
}

// bias[dir][j4] = bih + bhh (fp32)
__global__ void k_bias(const float* __restrict__ bfi, const float* __restrict__ bfh,
                       const float* __restrict__ bbi, const float* __restrict__ bbh,
                       float* __restrict__ bias) {
    int i = blockIdx.x * blockDim.x + threadIdx.x;
    if (i < 2048) {
        int d = i >> 10, j = i & 1023;
        const float* b1 = d ? bbi : bfi;
        const float* b2 = d ? bbh : bfh;
        bias[i] = b1[j] + b2[j];
    }
}

// ---------------- input GEMM:  G[16384][2048] = X[16384][608] * Wcat[2048][608]^T ----------------
__global__ __launch_bounds__(256) void k_gemm(const __hip_bfloat16* __restrict__ A,
                                              const __hip_bfloat16* __restrict__ Bw,
                                              __hip_bfloat16* __restrict__ C) {
    __shared__ __align__(16) unsigned short As[128 * 40];  // 128 x 32, row stride 40 (pad)
    __shared__ __align__(16) unsigned short Bs[128 * 40];
    int bm = blockIdx.x, bn = blockIdx.y;
    int row0 = bm * 128, col0 = bn * 128;
    int tid = threadIdx.x;
    int wave = tid >> 6, lane = tid & 63;
    int wm = (wave >> 1) * 64, wn = (wave & 1) * 64;
    int l15 = lane & 15, quad = lane >> 4;
    floatx4 acc[4][4];
    #pragma unroll
    for (int i = 0; i < 4; ++i)
        #pragma unroll
        for (int j = 0; j < 4; ++j) acc[i][j] = (floatx4){0.f, 0.f, 0.f, 0.f};

    int r1 = tid >> 2, p1 = tid & 3;  // staging: chunk row / 16B-part

    for (int kk = 0; kk < KPAD; kk += 32) {
        uint4 a0 = *(const uint4*)(A  + ((long)(row0 + r1))      * KPAD + kk + p1 * 8);
        uint4 a1 = *(const uint4*)(A  + ((long)(row0 + 64 + r1)) * KPAD + kk + p1 * 8);
        uint4 b0 = *(const uint4*)(Bw + ((long)(col0 + r1))      * KPAD + kk + p1 * 8);
        uint4 b1 = *(const uint4*)(Bw + ((long)(col0 + 64 + r1)) * KPAD + kk + p1 * 8);
        *(uint4*)&As[r1 * 40 + p1 * 8]        = a0;
        *(uint4*)&As[(64 + r1) * 40 + p1 * 8] = a1;
        *(uint4*)&Bs[r1 * 40 + p1 * 8]        = b0;
        *(uint4*)&Bs[(64 + r1) * 40 + p1 * 8] = b1;
        __syncthreads();
        bf16x8 af[4], bfr[4];
        #pragma unroll
        for (int tm = 0; tm < 4; ++tm)
            af[tm] = *(const bf16x8*)&As[(wm + tm * 16 + l15) * 40 + quad * 8];
        #pragma unroll
        for (int tn = 0; tn < 4; ++tn)
            bfr[tn] = *(const bf16x8*)&Bs[(wn + tn * 16 + l15) * 40 + quad * 8];
        #pragma unroll
        for (int tm = 0; tm < 4; ++tm)
            #pragma unroll
            for (int tn = 0; tn < 4; ++tn)
                acc[tm][tn] = __builtin_amdgcn_mfma_f32_16x16x32_bf16(af[tm], bfr[tn], acc[tm][tn], 0, 0, 0);
        __syncthreads();
    }
    // C/D layout: m = quad*4 + reg, n = lane&15
    #pragma unroll
    for (int tm = 0; tm < 4; ++tm)
        #pragma unroll
        for (int tn = 0; tn < 4; ++tn) {
            int m0 = row0 + wm + tm * 16 + quad * 4;
            int n  = col0 + wn + tn * 16 + l15;
            #pragma unroll
            for (int r = 0; r < 4; ++r)
                C[((long)(m0 + r)) * NG + n] = __float2bfloat16(acc[tm][tn][r]);
        }
}

// ---------------- LSTM recurrence ----------------
// One block per (batch, direction), 1024 threads = 16 waves.
// Thread (q = tid>>8, j = tid&255): partial over k in [q*64, q*64+64) of the
// 4 gate pre-activations for hidden column j; 4-way LDS reduction per step.
// R4: per-CU L2-fetch-queue-bound (~26 B/cyc/CU); fp8 weights halve bytes/step.
__global__ __launch_bounds__(1024) void k_lstm(const __hip_bfloat16* __restrict__ G,    // [MROWS][NG]
                                               const unsigned int* __restrict__ Wpk8,   // [2][256][256] fp8x4
                                               const float* __restrict__ bias,          // [2][1024]
                                               const int* __restrict__ lengths,
                                               __hip_bfloat16* __restrict__ Hout) {     // [B][T][512]
    int dir = blockIdx.x & 1;
    int b   = blockIdx.x >> 1;
    int tid = threadIdx.x;
    int q   = tid >> 8;        // k-quarter
    int j   = tid & 255;       // gate-unit column
    __shared__ float hs[HH];                        // holds h/16
    __shared__ __align__(16) float red[4][HH][4];   // [q][j][gate] = 16 KB
    float c = 0.f;
    float bi = 0.f, bf_ = 0.f, bg = 0.f, bo = 0.f;
    if (tid < HH) {
        const float* bs = bias + dir * 1024;
        bi = bs[j]; bf_ = bs[256 + j]; bg = bs[512 + j]; bo = bs[768 + j];
        hs[j] = 0.f;
    }
    int len = lengths[b];
    const unsigned int* wrow = Wpk8 + (long)dir * 65536 + q * 64 * 256 + j;
    const float* hq = hs + q * 64;
    __syncthreads();
    for (int t = 0; t < TT; ++t) {
        int tt = t;
        if (dir) tt = (t < len) ? (len - 1 - t) : t;
        const __hip_bfloat16* g = G + ((long)(b * TT + tt)) * NG + dir * 1024;
        float gi0 = 0.f, gi1 = 0.f, gi2 = 0.f, gi3 = 0.f;
        if (tid < HH) {   // prefetch gate inputs; consumed after the matvec
            gi0 = __bfloat162float(g[j]);
            gi1 = __bfloat162float(g[256 + j]);
            gi2 = __bfloat162float(g[512 + j]);
            gi3 = __bfloat162float(g[768 + j]);
        }
        float p0 = 0.f, p1 = 0.f, p2 = 0.f, p3 = 0.f;
        #pragma unroll 8
        for (int kk = 0; kk < 64; ++kk) {
            float hk = hq[kk];                 // LDS broadcast; = h/16
            unsigned int w = wrow[kk * 256];   // 64 lanes x 4B contiguous from L2
            p0 = fmaf(hk, __builtin_amdgcn_cvt_f32_fp8(w, 0), p0);   // 16*w_i
            p1 = fmaf(hk, __builtin_amdgcn_cvt_f32_fp8(w, 1), p1);   // 16*w_f
            p2 = fmaf(hk, __builtin_amdgcn_cvt_f32_fp8(w, 2), p2);   // 16*w_g
            p3 = fmaf(hk, __builtin_amdgcn_cvt_f32_fp8(w, 3), p3);   // 16*w_o
        }
        *(floatx4*)&red[q][j][0] = (floatx4){p0, p1, p2, p3};
        __syncthreads();
        if (tid < HH) {
            floatx4 r0 = *(const floatx4*)&red[0][j][0];
            floatx4 r1 = *(const floatx4*)&red[1][j][0];
            floatx4 r2 = *(const floatx4*)&red[2][j][0];
            floatx4 r3 = *(const floatx4*)&red[3][j][0];
            float ai = bi  + gi0 + r0[0] + r1[0] + r2[0] + r3[0];
            float af = bf_ + gi1 + r0[1] + r1[1] + r2[1] + r3[1];
            float ag = bg  + gi2 + r0[2] + r1[2] + r2[2] + r3[2];
            float ao = bo  + gi3 + r0[3] + r1[3] + r2[3] + r3[3];
            float ii = 1.f / (1.f + __expf(-ai));
            float ff = 1.f / (1.f + __expf(-af));
            float gg = tanhf(ag);
            float oo = 1.f / (1.f + __expf(-ao));
            c = ff * c + ii * gg;
            float h = oo * tanhf(c);
            hs[j] = h * 0.0625f;               // store h/16 for next step's matvec
            Hout[((long)(b * TT + tt)) * 512 + dir * HH + j] = __float2bfloat16(h);
        }
        __syncthreads();
    }
}

// ---------------- emissions: E[row][l] = h[row][0..511] . Wlin[l][0..511] + blin[l] ----------------
__global__ void k_emis(const __hip_bfloat16* __restrict__ Hc,   // [MROWS][512]
                       const float* __restrict__ Wlin,          // [15][512] fp32
                       const float* __restrict__ blin,
                       float* __restrict__ E) {
    int gid = blockIdx.x * blockDim.x + threadIdx.x;
    if (gid >= MROWS * LL) return;
    int row = gid / LL;
    int l = gid - row * LL;
    const __hip_bfloat16* hr = Hc + (long)row * 512;
    const float* wr = Wlin + l * 512;
    float s = blin[l];
    #pragma unroll 8
    for (int k = 0; k < 512; ++k)
        s = fmaf(__bfloat162float(hr[k]), wr[k], s);
    E[gid] = s;
}

// ---------------- CRF NLL per batch: one wave per batch ----------------
__global__ void k_crf(const float* __restrict__ E,      // [B][T][15]
                      const int* __restrict__ tags,     // [B][T]
                      const int* __restrict__ lengths,
                      const float* __restrict__ start_t,
                      const float* __restrict__ end_t,
                      const float* __restrict__ trans,  // [15][15] fp32
                      float* __restrict__ outp) {
    int b = blockIdx.x;
    int lane = threadIdx.x;
    int len = lengths[b];
    const float* Eb = E + (long)b * TT * LL;
    const int* tg = tags + b * TT;
    float tcol[LL];
    #pragma unroll
    for (int k = 0; k < LL; ++k)
        tcol[k] = (lane < LL) ? trans[k * LL + lane] : 0.f;
    float alpha = (lane < LL) ? start_t[lane] + Eb[lane] : -1e30f;
    for (int t = 1; t < len; ++t) {
        float e = (lane < LL) ? Eb[t * LL + lane] : 0.f;
        float m = -1e30f;
        float v[LL];
        #pragma unroll
        for (int k = 0; k < LL; ++k) {
            float ak = __shfl(alpha, k, 64);
            v[k] = ak + tcol[k];
            m = fmaxf(m, v[k]);
        }
        float s = 0.f;
        #pragma unroll
        for (int k = 0; k < LL; ++k) s += __expf(v[k] - m);
        alpha = m + __logf(s) + e;
    }
    // denominator
    float z = alpha + ((lane < LL) ? end_t[lane] : -1e30f);
    float m2 = -1e30f;
    #pragma unroll
    for (int k = 0; k < LL; ++k) m2 = fmaxf(m2, __shfl(z, k, 64));
    float s2 = 0.f;
    #pragma unroll
    for (int k = 0; k < LL; ++k) s2 += __expf(__shfl(z, k, 64) - m2);
    float den = m2 + __logf(s2);
    // numerator (lane-parallel over t, then wave-reduce)
    float part = 0.f;
    for (int t = lane; t < TT; t += 64) {
        if (t < len) {
            int tag = tg[t];
            part += Eb[t * LL + tag];
            if (t >= 1) part += trans[tg[t - 1] * LL + tag];
        }
    }
    #pragma unroll
    for (int off = 32; off > 0; off >>= 1) part += __shfl_down(part, off, 64);
    if (lane == 0) {
        float num = part + start_t[tg[0]] + end_t[tg[len - 1]];
        outp[b] = num - den;
    }
}

// output is float32 (reference output dtype)
__global__ void k_final(const float* __restrict__ outp, float* __restrict__ out) {
    int lane = threadIdx.x;
    float v = outp[lane];
    #pragma unroll
    for (int off = 32; off > 0; off >>= 1) v += __shfl_down(v, off, 64);
    if (lane == 0) out[0] = -v;   // loss = -sum(num - den)
}

// ---------------- launch ----------------
extern "C" void kernel_launch(void* const* d_in, const int* in_sizes, int n_in,
                              void* d_out, int out_size, void* d_ws, size_t ws_size,
                              hipStream_t stream) {
    const int* input_ids    = (const int*)d_in[0];
    const int* lengths      = (const int*)d_in[1];
    const int* softword_ids = (const int*)d_in[2];
    const int* label_ids    = (const int*)d_in[3];
    const float* emb      = (const float*)d_in[4];
    const float* soft_emb = (const float*)d_in[5];
    const float* Wih_f = (const float*)d_in[6];
    const float* Whh_f = (const float*)d_in[7];
    const float* bih_f = (const float*)d_in[8];
    const float* bhh_f = (const float*)d_in[9];
    const float* Wih_b = (const float*)d_in[10];
    const float* Whh_b = (const float*)d_in[11];
    const float* bih_b = (const float*)d_in[12];
    const float* bhh_b = (const float*)d_in[13];
    const float* Wlin  = (const float*)d_in[14];
    const float* blin  = (const float*)d_in[15];
    const float* start_t = (const float*)d_in[16];
    const float* end_t   = (const float*)d_in[17];
    const float* trans   = (const float*)d_in[18];

    // workspace layout, small buffers first (all offsets 256B aligned)
    char* base = (char*)d_ws;
    float*          part = (float*)(base);                             // 64*4          =        256
    float*          bias = (float*)(base + 256);                       // 2*1024*4      =      8,192
    float*          E    = (float*)(base + 8448);                      // 16384*15*4    =    983,040
    unsigned int*   Wpk8 = (unsigned int*)(base + 991488);             // 2*256*256*4   =    524,288 (region reserves 1 MB)
    __hip_bfloat16* Wcat = (__hip_bfloat16*)(base + 2040064);          // 2048*608*2    =  2,490,368
    __hip_bfloat16* Hc   = (__hip_bfloat16*)(base + 4530432);          // 64*256*512*2  = 16,777,216
    __hip_bfloat16* X    = (__hip_bfloat16*)(base + 21307648);         // 16384*608*2   = 19,922,944
    __hip_bfloat16* G    = (__hip_bfloat16*)(base + 41230592);         // 16384*2048*2  = 67,108,864
                                                                       // end: 108,339,456

    k_embed<<<MROWS, 64, 0, stream>>>(input_ids, softword_ids, emb, soft_emb, X);
    k_wcat<<<NG, 64, 0, stream>>>(Wih_f, Wih_b, Wcat);
    k_wpk<<<512, 256, 0, stream>>>(Whh_f, Whh_b, Wpk8);
    k_bias<<<8, 256, 0, stream>>>(bih_f, bhh_f, bih_b, bhh_b, bias);
    k_gemm<<<dim3(MROWS / 128, NG / 128), 256, 0, stream>>>(X, Wcat, G);
    k_lstm<<<BB * 2, 1024, 0, stream>>>(G, Wpk8, bias, lengths, Hc);
    k_emis<<<(MROWS * LL) / 256, 256, 0, stream>>>(Hc, Wlin, blin, E);
    k_crf<<<BB, 64, 0, stream>>>(E, label_ids, lengths, start_t, end_t, trans, part);
    k_final<<<1, 64, 0, stream>>>(part, (float*)d_out);
}